// Round 4
// baseline (883.266 us; speedup 1.0000x reference)
//
#include <hip/hip_runtime.h>
#include <hip/hip_bf16.h>

// GRU4REC final-state kernel, persistent-register-weight design.
// B=1024, T=256, D=64, H=128.  Inputs fp32 (confirmed r1/r3), compute fp32,
// output fp32 (reference's output dtype; harness compares at bf16 granularity).
//
// 256 blocks x 1024 threads: one block per CU, G=4 batch rows per block.
// Weights live in VGPRs (72 f32/thread = exactly one full copy per CU).
// Activations (x|h, x|r*h) broadcast from LDS; 16-way k-split partials
// reduced through LDS.  x_{t+1} prefetched by lanes idle in phase D.

#define T_  256
#define D_  64
#define H_  128
#define DH_ 192
#define G_  4

__global__ __launch_bounds__(1024, 4) void gru_persist(
    const int* __restrict__ item_his,          // [1024][256]
    const int* __restrict__ seq_lens,          // [1024]
    const float* __restrict__ emb,             // [1e6][64]
    const float* __restrict__ Wg,              // [192][256]
    const float* __restrict__ bg,              // [256]
    const float* __restrict__ Wc,              // [192][128]
    const float* __restrict__ bc,              // [128]
    float* __restrict__ out)                   // [1024][128] fp32
{
    __shared__ float XH[G_][DH_];        // [x_t | h]
    __shared__ float XC[G_][DH_];        // [x_t | r*h]
    __shared__ float U[G_][H_];          // update gate
    __shared__ float P[16][G_][256];     // gate partials  (64 KB)
    __shared__ float P2[16][G_][128];    // cand partials  (32 KB)

    const int tid  = threadIdx.x;
    const int row0 = blockIdx.x * G_;

    // ---- thread mapping for the dot phases ----
    const int jg  = tid & 63;        // j-group within wave (lane)
    const int kc  = tid >> 6;        // k-chunk 0..15 (wave index)
    const int j0  = jg * 4;          // gate: 4 consecutive j
    const int j0c = jg * 2;          // cand: 2 consecutive j
    const int k0  = kc * 12;         // 12 k per chunk (16*12 = 192)

    // ---- load weights into registers (one full copy per CU) ----
    float wg[12][4];
    float wc[12][2];
    #pragma unroll
    for (int kk = 0; kk < 12; ++kk) {
        const float4 g4 = *(const float4*)(Wg + (k0 + kk) * 256 + j0);
        wg[kk][0] = g4.x; wg[kk][1] = g4.y; wg[kk][2] = g4.z; wg[kk][3] = g4.w;
        const float2 c2 = *(const float2*)(Wc + (k0 + kk) * 128 + j0c);
        wc[kk][0] = c2.x; wc[kk][1] = c2.y;
    }

    const float bgB = bg[tid & 255];   // for phase B (r=tid>>8, j=tid&255)
    const float bcB = bc[tid & 127];   // for phase D (r=tid>>7, j=tid&127)

    // ---- sequence lengths ----
    int len0 = seq_lens[row0 + 0];
    int len1 = seq_lens[row0 + 1];
    int len2 = seq_lens[row0 + 2];
    int len3 = seq_lens[row0 + 3];
    const int maxlen = max(max(len0, len1), max(len2, len3));
    int lenArr[4] = {len0, len1, len2, len3};
    const int lenD = lenArr[(tid >> 7) & 3];

    // ---- init: h = 0, x_0 into XH/XC ----
    if (tid < 512) {
        const int r = tid >> 7, j = tid & 127;
        XH[r][64 + j] = 0.f;
    }
    const bool isLoader = (tid >= 512 && tid < 768);
    const int  lr = (tid >> 6) & 3;  // loader row (tid 512..767 -> 0..3)
    const int  ld = tid & 63;        // loader dim
    if (isLoader && maxlen > 0) {
        const int idx = item_his[(row0 + lr) * T_ + 0];
        const float x = emb[idx * D_ + ld];
        XH[lr][ld] = x;
        XC[lr][ld] = x;
    }
    __syncthreads();

    for (int t = 0; t < maxlen; ++t) {
        // ---- prefetch x_{t+1} (committed to LDS during phase D) ----
        float xn = 0.f;
        const int tn = t + 1;
        if (isLoader && tn < T_) {
            const int idx = item_his[(row0 + lr) * T_ + tn];
            xn = emb[idx * D_ + ld];
        }

        // ---- Phase A: gate partials  P[kc][r][j] = sum_{k in chunk} xh[k]*Wg[k][j]
        #pragma unroll
        for (int r = 0; r < G_; ++r) {
            float a0 = 0.f, a1 = 0.f, a2 = 0.f, a3 = 0.f;
            #pragma unroll
            for (int kk4 = 0; kk4 < 3; ++kk4) {
                const float4 qv = *(const float4*)&XH[r][k0 + kk4 * 4];
                const float qq[4] = {qv.x, qv.y, qv.z, qv.w};
                #pragma unroll
                for (int m = 0; m < 4; ++m) {
                    const int kk = kk4 * 4 + m;
                    a0 += qq[m] * wg[kk][0];
                    a1 += qq[m] * wg[kk][1];
                    a2 += qq[m] * wg[kk][2];
                    a3 += qq[m] * wg[kk][3];
                }
            }
            float4 o = {a0, a1, a2, a3};
            *(float4*)&P[kc][r][j0] = o;
        }
        __syncthreads();

        // ---- Phase B: reduce gates, sigmoid, build r*h and u ----
        {
            const int rB = tid >> 8;     // 0..3
            const int jB = tid & 255;    // 0..255
            float s = bgB;
            #pragma unroll
            for (int q = 0; q < 16; ++q) s += P[q][rB][jB];
            const float g = 1.f / (1.f + __expf(-s));
            if (jB < 128) {
                XC[rB][64 + jB] = g * XH[rB][64 + jB];   // r * h
            } else {
                U[rB][jB - 128] = g;                      // u
            }
        }
        __syncthreads();

        // ---- Phase C: cand partials  P2[kc][r][j] = sum xrh[k]*Wc[k][j]
        #pragma unroll
        for (int r = 0; r < G_; ++r) {
            float c0 = 0.f, c1 = 0.f;
            #pragma unroll
            for (int kk4 = 0; kk4 < 3; ++kk4) {
                const float4 qv = *(const float4*)&XC[r][k0 + kk4 * 4];
                const float qq[4] = {qv.x, qv.y, qv.z, qv.w};
                #pragma unroll
                for (int m = 0; m < 4; ++m) {
                    const int kk = kk4 * 4 + m;
                    c0 += qq[m] * wc[kk][0];
                    c1 += qq[m] * wc[kk][1];
                }
            }
            float2 o2 = {c0, c1};
            *(float2*)&P2[kc][r][j0c] = o2;
        }
        __syncthreads();

        // ---- Phase D: reduce cand, tanh, h update (masked); loaders commit x_{t+1}
        if (tid < 512) {
            const int rD = tid >> 7;
            const int jD = tid & 127;
            float s = bcB;
            #pragma unroll
            for (int q = 0; q < 16; ++q) s += P2[q][rD][jD];
            s = fminf(fmaxf(s, -15.f), 15.f);
            const float e = __expf(2.f * s);
            const float c = (e - 1.f) / (e + 1.f);        // tanh
            const float u = U[rD][jD];
            float h = XH[rD][64 + jD];
            if (t < lenD) h = u * h + (1.f - u) * c;
            XH[rD][64 + jD] = h;
        } else if (isLoader && tn < T_) {
            XH[lr][ld] = xn;
            XC[lr][ld] = xn;
        }
        __syncthreads();
    }

    // ---- write final h (fp32) ----
    if (tid < 512) {
        const int rD = tid >> 7;
        const int jD = tid & 127;
        out[(row0 + rD) * H_ + jD] = XH[rD][64 + jD];
    }
}

extern "C" void kernel_launch(void* const* d_in, const int* in_sizes, int n_in,
                              void* d_out, int out_size, void* d_ws, size_t ws_size,
                              hipStream_t stream) {
    const int*   item_his = (const int*)d_in[0];
    const int*   seq_lens = (const int*)d_in[1];
    const float* emb      = (const float*)d_in[2];
    const float* Wg       = (const float*)d_in[3];
    const float* bg       = (const float*)d_in[4];
    const float* Wc       = (const float*)d_in[5];
    const float* bc       = (const float*)d_in[6];
    float*       out      = (float*)d_out;

    gru_persist<<<256, 1024, 0, stream>>>(item_his, seq_lens, emb, Wg, bg, Wc, bc, out);
}